// Round 4
// baseline (383.139 us; speedup 1.0000x reference)
//
#include <hip/hip_runtime.h>

typedef unsigned short ushort_t;
typedef short v8s __attribute__((ext_vector_type(8)));   // 8 bf16 (4 VGPRs)
typedef float v4f __attribute__((ext_vector_type(4)));   // MFMA acc

#define BATCH    65536
#define UNITS    256
#define M_TILE   64
#define KSTEPS   16
#define BCHUNK   10240      // shorts per packed-K chunk: 256 cols * (32k + 8 pad)
#define BCHUNK_B 20480      // bytes per chunk
#define LDS_SC   40960      // scalar region offset (after 2 B-buffers)
#define LDS_TOT  42752

__device__ __forceinline__ float b2f(ushort_t u) {
    union { unsigned int i; float f; } v; v.i = ((unsigned int)u) << 16; return v.f;
}
__device__ __forceinline__ ushort_t f2b(float f) {
    union { float f; unsigned int i; } v; v.f = f;
    unsigned int r = (v.i + 0x7fffu + ((v.i >> 16) & 1u)) >> 16;   // RNE
    return (ushort_t)r;
}
__device__ __forceinline__ v8s cvt8(float4 f0, float4 f1) {
    v8s a;
    a[0] = (short)f2b(f0.x); a[1] = (short)f2b(f0.y);
    a[2] = (short)f2b(f0.z); a[3] = (short)f2b(f0.w);
    a[4] = (short)f2b(f1.x); a[5] = (short)f2b(f1.y);
    a[6] = (short)f2b(f1.z); a[7] = (short)f2b(f1.w);
    return a;
}
// async global->LDS, 16 B per lane, lane-contiguous (wave-uniform base + lane*16)
__device__ __forceinline__ void cp16_async(char* lds, const char* g) {
    __builtin_amdgcn_global_load_lds(
        (const __attribute__((address_space(1))) unsigned int*)g,
        (__attribute__((address_space(3))) unsigned int*)lds, 16, 0, 0);
}

// ---- weight pre-pack: fp32 W[512][256] -> bf16 per-chunk [n][kl] -----------
// chunk c = k>>5 holds cols n=0..255, each 32 k-values + 8 pad (16B-aligned)
__global__ void pack_w(const float* __restrict__ w_in,
                       const float* __restrict__ w_rec,
                       ushort_t* __restrict__ Wp) {
    int gid = blockIdx.x * 256 + threadIdx.x;      // 0..131071
    int k = gid >> 8, n = gid & 255;
    float v = (k < 256) ? w_in[k * 256 + n] : w_rec[(k - 256) * 256 + n];
    Wp[(size_t)(k >> 5) * BCHUNK + n * 40 + (k & 31)] = f2b(v);
}

// ---- fused cell ------------------------------------------------------------
__global__ __launch_bounds__(256, 3)
void fused_cell(const float* __restrict__ inputs,
                const float* __restrict__ prev_h,
                const float* __restrict__ prev_G,
                const float* __restrict__ prev_phase,
                const ushort_t* __restrict__ Wp,
                const float* __restrict__ bias,
                float* __restrict__ out) {
    __shared__ __align__(16) char smem[LDS_TOT];
    short* Bbuf   = (short*)(smem);               // 2 x 20480 B chunk images
    float* r_mean = (float*)(smem + LDS_SC);
    float* r_rstd = r_mean + 64;
    float* r_comb = r_rstd + 64;
    float* bias_f = r_comb + 64;

    const int tid  = threadIdx.x;
    const int l    = tid & 63;
    const int w    = tid >> 6;
    const int row0 = blockIdx.x * M_TILE;

    float* outH = out;
    float* outG = out + (size_t)BATCH * UNITS;
    float* outP = out + (size_t)2 * BATCH * UNITS;

    // prefetch B chunk 0 into buf0 (overlaps all of phase 1)
    {
        const char* g = (const char*)Wp;
        #pragma unroll
        for (int j = 0; j < 5; ++j) {
            int off = j * 4096 + tid * 16;
            cp16_async(smem + off, g + off);
        }
    }

    bias_f[tid] = bias[tid];

    // ---- phase 1: new_G = 0.9*prev_G + 0.1*roll(prev_h), row stats, oscillator
    for (int rr = 0; rr < 16; ++rr) {
        int lr = w * 16 + rr;
        int gr = row0 + lr;
        int c0 = l * 4;
        int pc = (c0 + 128) & 255;        // raw[:,c] = prev_h[:,(c+128)&255]
        float4 hp = *(const float4*)(prev_h + (size_t)gr * UNITS + pc);
        float4 gp = *(const float4*)(prev_G + (size_t)gr * UNITS + c0);
        float4 ng;
        ng.x = 0.9f * gp.x + 0.1f * hp.x;
        ng.y = 0.9f * gp.y + 0.1f * hp.y;
        ng.z = 0.9f * gp.z + 0.1f * hp.z;
        ng.w = 0.9f * gp.w + 0.1f * hp.w;
        float s1 = ng.x + ng.y + ng.z + ng.w;
        float s2 = ng.x*ng.x + ng.y*ng.y + ng.z*ng.z + ng.w*ng.w;
        float sh = hp.x + hp.y + hp.z + hp.w;
        *(float4*)(outG + (size_t)gr * UNITS + c0) = ng;          // output 1 (fp32)
        #pragma unroll
        for (int off = 32; off > 0; off >>= 1) {
            s1 += __shfl_xor(s1, off, 64);
            s2 += __shfl_xor(s2, off, 64);
            sh += __shfl_xor(sh, off, 64);
        }
        if (l == 0) {
            float mean = s1 * (1.f / 256.f);
            float var  = s2 * (1.f / 256.f) - mean * mean;         // population var
            float rstd = 1.f / (sqrtf(fmaxf(var, 0.f)) + 1e-6f);
            float np   = prev_phase[gr] + 0.2513274122871834591f;  // 2*pi/25
            outP[gr] = np;                                          // output 2 (fp32)
            float comb = sinf(np) + 0.05f * (sh * (1.f / 256.f) - 0.1f);
            r_mean[lr] = mean; r_rstd[lr] = rstd; r_comb[lr] = comb;
        }
    }

    __syncthreads();   // scalars visible; B chunk 0 landed (vmcnt drained)

    // ---- phase 2: GEMM z = [inputs|prev_h] @ [w_in;w_rec]  (bf16 MFMA)
    // 16x16x32: A[m=lane&15][k=q*8+j]; B[k=q*8+j][n=lane&15]; C: col=lane&15,row=q*4+reg
    const int n16 = l & 15;
    const int q   = l >> 4;
    v4f acc[16];
    const v4f z4 = {0.f, 0.f, 0.f, 0.f};
    #pragma unroll
    for (int t = 0; t < 16; ++t) acc[t] = z4;

    const int arow = w * 16 + n16;
    const float* ainp = inputs + (size_t)(row0 + arow) * UNITS + q * 8;
    const float* ahp  = prev_h + (size_t)(row0 + arow) * UNITS + q * 8;

    // A frag for s=0 (raw), converted before the loop
    v8s a_cur = cvt8(*(const float4*)(ainp), *(const float4*)(ainp + 4));

    for (int s = 0; s < KSTEPS; ++s) {
        float4 f0n, f1n;
        if (s + 1 < KSTEPS) {
            // prefetch next B chunk into the other LDS buffer (async)
            const char* g = (const char*)(Wp + (size_t)(s + 1) * BCHUNK);
            char* lp = smem + ((s + 1) & 1) * BCHUNK_B;
            #pragma unroll
            for (int j = 0; j < 5; ++j) {
                int off = j * 4096 + tid * 16;
                cp16_async(lp + off, g + off);
            }
            // issue next A raw loads early (complete by the barrier)
            int sn = s + 1;
            const float* ap = (sn < 8) ? (ainp + sn * 32) : (ahp + (sn - 8) * 32);
            f0n = *(const float4*)(ap);
            f1n = *(const float4*)(ap + 4);
        }
        const short* bb = Bbuf + (s & 1) * BCHUNK + n16 * 40 + q * 8;
        #pragma unroll
        for (int t = 0; t < 16; ++t) {
            v8s b = *(const v8s*)(bb + t * 640);   // col = t*16+n16, k = q*8+j
            acc[t] = __builtin_amdgcn_mfma_f32_16x16x32_bf16(a_cur, b, acc[t], 0, 0, 0);
        }
        __syncthreads();   // all waves done with buf[s&1]; next chunk landed
        if (s + 1 < KSTEPS) a_cur = cvt8(f0n, f1n);
    }

    // ---- epilogue: field_effect * (dot+bias) -> elu -> inertia -> clip
    #pragma unroll
    for (int t = 0; t < 16; ++t) {
        int c = t * 16 + n16;
        float bz = bias_f[c];
        #pragma unroll
        for (int r = 0; r < 4; ++r) {
            int lr = w * 16 + q * 4 + r;
            int gr = row0 + lr;
            float gval = outG[(size_t)gr * UNITS + c];     // own store, XCD-L2 hot
            float gn = (gval - r_mean[lr]) * r_rstd[lr];
            float e2 = __expf(2.f * gn);                   // tanh via exp
            float th = 1.f - 2.f / (e2 + 1.f);
            float field = 1.f + 0.5f * r_comb[lr] * th;
            float z = (acc[t][r] + bz) * field;
            float el = (z > 0.f) ? z : (__expf(z) - 1.f);
            float h = 0.9f * prev_h[(size_t)gr * UNITS + c] + 0.1f * el;
            h = fminf(fmaxf(h, -20.f), 20.f);
            outH[(size_t)gr * UNITS + c] = h;              // output 0 (fp32)
        }
    }
}

extern "C" void kernel_launch(void* const* d_in, const int* in_sizes, int n_in,
                              void* d_out, int out_size, void* d_ws, size_t ws_size,
                              hipStream_t stream) {
    const float* inputs     = (const float*)d_in[0];
    const float* prev_h     = (const float*)d_in[1];
    const float* prev_G     = (const float*)d_in[2];
    const float* prev_phase = (const float*)d_in[3];
    const float* w_in       = (const float*)d_in[4];
    const float* w_rec      = (const float*)d_in[5];
    const float* bias       = (const float*)d_in[6];
    float* out    = (float*)d_out;
    ushort_t* Wp  = (ushort_t*)d_ws;       // 327,680 B packed bf16 weights

    pack_w<<<512, 256, 0, stream>>>(w_in, w_rec, Wp);
    fused_cell<<<BATCH / M_TILE, 256, 0, stream>>>(inputs, prev_h, prev_G,
                                                   prev_phase, Wp, bias, out);
}